// Round 3
// baseline (167.282 us; speedup 1.0000x reference)
//
#include <hip/hip_runtime.h>

#define NORB   12
#define NFEAT  14
#define NCOL1  144
#define NCOL2  20736
#define RPB    192          // threads per block
#define NSPLIT 9            // two-body chunks per sample (9*192 = 1728 rows)
#define CPS    (NSPLIT + 1) // blocks per sample (chunk 0 = prep)
#define NT     256          // samples
#define CTR_OFF ((2 * NT + NT * NSPLIT) * 8)

extern "C" __global__ void __launch_bounds__(RPB)
eloc_fused(const float* __restrict__ mfv, const float* __restrict__ h1,
           const float* __restrict__ h2, const int* __restrict__ vn,
           const float* __restrict__ w,
           double* __restrict__ ep, double* __restrict__ part,
           unsigned* __restrict__ ctr, float* __restrict__ out)
{
    const int tid = threadIdx.x;
    const int bid = blockIdx.x;
    const int t   = bid / CPS;
    const int ch  = bid % CPS;

    __shared__ float phi_s[NORB][NFEAT];
    __shared__ float ps_s[NORB];
    __shared__ int   x_s[NORB];
    __shared__ float Sv_s;
    __shared__ float W_s[NFEAT][NFEAT];
    __shared__ float tmp_s[NORB][NFEAT];
    __shared__ float G_s[NORB][NORB];
    __shared__ unsigned char m1_s[NCOL1];
    __shared__ int Ri_s[NORB], Rj_s[NORB], M_s;
    __shared__ double A1[NORB][NORB], A2[NORB][NORB];
    __shared__ double red_s[RPB / 64];
    __shared__ double det_s[2];
    __shared__ double h1sum_s;
    __shared__ double se_s[NT], sp_s[NT];
    __shared__ int last_s;

    // ---- common: phi, x, ps, Sv, X2 ----
    if (tid < NORB * NFEAT)
        phi_s[tid / NFEAT][tid % NFEAT] = mfv[(size_t)t * NORB * NFEAT + tid];
    if (tid >= NORB * NFEAT && tid < NORB * NFEAT + NORB)
        x_s[tid - NORB * NFEAT] = vn[t * NORB + (tid - NORB * NFEAT)];
    __syncthreads();
    if (tid < NORB) {
        float s = 0.f;
        #pragma unroll
        for (int f = 0; f < NFEAT; ++f) s += phi_s[tid][f];
        ps_s[tid] = s;
    }
    __syncthreads();
    if (tid == 0) {
        float s = 0.f;
        for (int a = 0; a < NORB; ++a) s += ps_s[a] * (float)x_s[a];
        Sv_s = s;
    }
    __syncthreads();

    int X2 = 0;
    #pragma unroll
    for (int a = 0; a < NORB; ++a) X2 |= (x_s[a] == 2) ? (1 << a) : 0;
    const int nx2 = ~X2 & 0xFFF;
    const float Sv = Sv_s;

    if (ch != 0) {
        // ---------------- two-body chunk ----------------
        float psv[NORB];
        #pragma unroll
        for (int q = 0; q < NORB; ++q) psv[q] = ps_s[q];

        const int r = (ch - 1) * RPB + tid;             // 0..1727
        const int i = r / 144, j = (r / NORB) % NORB, p = r % NORB;

        const float4* hr = (const float4*)(h2 + (size_t)t * NCOL2 + (size_t)r * NORB);
        const float4 ha = hr[0], hb = hr[1], hc = hr[2];

        const int bi = 1 << i, bj = 1 << j, bp = 1 << p;
        const int um0 = 0xFFF & ~(bi | bj | bp);
        const int xi = 1 + ((X2 >> i) & 1);
        const int xj = 1 + ((X2 >> j) & 1);
        const int xp = 1 + ((X2 >> p) & 1);
        const int basei = xi + 1 - ((bi >> j) & 1) - ((bi >> p) & 1);
        const int basej = xj + ((bj >> i) & 1) - 1 - ((bj >> p) & 1);
        const int basep = xp + ((bp >> i) & 1) - ((bp >> j) & 1) - 1;
        const float a2b = Sv + psv[i] - psv[j] - psv[p];

        float acc = 0.f;
#define COLQ(q, hv) {                                                       \
        const int bq  = 1 << (q);                                           \
        const int um  = um0 & ~bq;                                          \
        const int hm1 = nx2 & um, hm2 = X2 & um;                            \
        int mn = hm1 ? 1 : (hm2 ? 2 : 9);                                   \
        int mx = hm2 ? 2 : (hm1 ? 1 : -9);                                  \
        const int iq = (bi >> (q)) & 1, jq = (bj >> (q)) & 1,               \
                  pq = (bp >> (q)) & 1;                                     \
        const int vi = basei + iq, vj = basej + jq, vp = basep + pq;        \
        const int xq = 1 + ((X2 >> (q)) & 1);                               \
        const int vq = xq + 1 + iq - jq - pq;                               \
        mn = min(min(mn, vi), min(vj, min(vp, vq)));                        \
        mx = max(max(mx, vi), max(vj, max(vp, vq)));                        \
        const bool ok = (mx - mn == 1) && ((hv) > 0.0f);                    \
        const float tq = ok ? (hv) * (a2b + psv[q]) : 0.0f;                 \
        acc = fmaf(tq, tq, acc);                                            \
    }
        COLQ(0,  ha.x)  COLQ(1,  ha.y)  COLQ(2,  ha.z)  COLQ(3,  ha.w)
        COLQ(4,  hb.x)  COLQ(5,  hb.y)  COLQ(6,  hb.z)  COLQ(7,  hb.w)
        COLQ(8,  hc.x)  COLQ(9,  hc.y)  COLQ(10, hc.z)  COLQ(11, hc.w)
#undef COLQ

        double accd = (double)acc;
        #pragma unroll
        for (int o = 32; o > 0; o >>= 1) accd += __shfl_down(accd, o, 64);
        const int wv = tid >> 6, lane = tid & 63;
        if (lane == 0) red_s[wv] = accd;
        __syncthreads();
        if (tid == 0) part[t * NSPLIT + (ch - 1)] = red_s[0] + red_s[1] + red_s[2];
    } else {
        // ---------------- prep chunk: G, one-body, determinants ----------------
        for (int k2 = tid; k2 < NFEAT * NFEAT; k2 += RPB) {
            int r2 = k2 / NFEAT, c2 = k2 % NFEAT;
            W_s[r2][c2] = w[k2] + w[c2 * NFEAT + r2];
        }
        __syncthreads();
        if (tid < NORB * NFEAT) {
            int a = tid / NFEAT, f = tid % NFEAT;
            float s = 0.f;
            #pragma unroll
            for (int g = 0; g < NFEAT; ++g) s += phi_s[a][g] * W_s[g][f];
            tmp_s[a][f] = s;
        }
        __syncthreads();
        if (tid < NCOL1) {
            int a = tid / NORB, i = tid % NORB;
            float s = 0.f;
            #pragma unroll
            for (int f = 0; f < NFEAT; ++f) s += tmp_s[a][f] * phi_s[i][f];
            G_s[a][i] = s;
        }

        // one-body mask + h1^2 sum
        double h1c = 0.0;
        if (tid < NCOL1) {
            int ii = tid / NORB, jj = tid % NORB;
            int um  = 0xFFF & ~((1 << ii) | (1 << jj));
            int hm1 = nx2 & um, hm2 = X2 & um;
            int mn = hm1 ? 1 : (hm2 ? 2 : 9);
            int mx = hm2 ? 2 : (hm1 ? 1 : -9);
            int d  = (ii == jj) ? 0 : 1;
            int vi = x_s[ii] - d, vj = x_s[jj] + d;
            mn = min(mn, min(vi, vj));
            mx = max(mx, max(vi, vj));
            float h1v = h1[(size_t)t * NCOL1 + tid];
            bool ok = (mx - mn == 1) && (h1v > 0.0f);
            m1_s[tid] = ok ? 1 : 0;
            if (ok) h1c = (double)h1v * (double)h1v;
        }
        __syncthreads();
        {
            #pragma unroll
            for (int o = 32; o > 0; o >>= 1) h1c += __shfl_down(h1c, o, 64);
            const int wv = tid >> 6, lane = tid & 63;
            if (lane == 0) red_s[wv] = h1c;
            __syncthreads();
            if (tid == 0) h1sum_s = red_s[0] + red_s[1] + red_s[2];
        }

        if (tid < NORB) {
            int ri = 0, rj = 0;
            #pragma unroll
            for (int o = 0; o < NORB; ++o) {
                ri += m1_s[tid * NORB + o];
                rj += m1_s[o * NORB + tid];
            }
            Ri_s[tid] = ri;
            Rj_s[tid] = rj;
        }
        __syncthreads();
        if (tid == 0) {
            int m = 0;
            #pragma unroll
            for (int o = 0; o < NORB; ++o) m += Ri_s[o];
            M_s = m;
        }
        __syncthreads();

        if (tid < NCOL1) {
            int a = tid / NORB, b = tid % NORB;
            int xa = x_s[a], xb = x_s[b];
            int Da = Rj_s[a] - Ri_s[a], Db = Rj_s[b] - Ri_s[b];
            int s1 = xa * xb * M_s + xa * Db + xb * Da
                   - (int)m1_s[b * NORB + a] - (int)m1_s[a * NORB + b];
            if (a == b) s1 += Rj_s[a] + Ri_s[a];
            A1[a][b] = (double)G_s[a][b] * (double)s1;
            A2[a][b] = (double)G_s[a][b];
        }
        __syncthreads();

        // barrier-free in-register LU with partial pivoting; wave0: A1, wave1: A2
        const int wv = tid >> 6, lane = tid & 63;
        if (wv < 2) {
            const double* Abase = (wv == 0) ? &A1[0][0] : &A2[0][0];
            const int rl = (lane < NORB) ? lane : 0;
            double a[NORB];
            #pragma unroll
            for (int c = 0; c < NORB; ++c) a[c] = Abase[rl * NORB + c];
            double det = 1.0;
            #pragma unroll
            for (int k = 0; k < NORB; ++k) {
                double key = (lane >= k && lane < NORB) ? fabs(a[k]) : -1.0;
                int idx = lane;
                #pragma unroll
                for (int off = 8; off >= 1; off >>= 1) {
                    double k2 = __shfl_xor(key, off);
                    int    i2 = __shfl_xor(idx, off);
                    if (k2 > key || (k2 == key && i2 < idx)) { key = k2; idx = i2; }
                }
                int pr = idx;
                if (pr != k) det = -det;
                int src = (lane == k) ? pr : ((lane == pr) ? k : lane);
                #pragma unroll
                for (int c = 0; c < NORB; ++c) a[c] = __shfl(a[c], src);
                double pk[NORB];
                #pragma unroll
                for (int c = 0; c < NORB; ++c) pk[c] = __shfl(a[c], k);
                double piv = pk[k];
                det *= piv;
                double inv = (piv != 0.0) ? 1.0 / piv : 0.0;
                double f = (lane > k && lane < NORB) ? a[k] * inv : 0.0;
                #pragma unroll
                for (int c = 0; c < NORB; ++c) a[c] = fma(-f, pk[c], a[c]);
            }
            if (lane == 0) det_s[wv] = det;
        }
        __syncthreads();

        if (tid == 0) {
            double e1 = det_s[0] * det_s[0] * h1sum_s;
            int n2 = __popc(X2);
            double pd = det_s[1] * (double)(1ull << (2 * n2));
            ep[2 * t]     = e1;
            ep[2 * t + 1] = pd * pd;
        }
    }

    // ---------------- completion: last block finalizes ----------------
    __threadfence();
    if (tid == 0) {
        unsigned old = atomicAdd(ctr, 1u);
        last_s = (old == (unsigned)(gridDim.x - 1)) ? 1 : 0;
    }
    __syncthreads();
    if (last_s) {
        __threadfence();   // acquire: invalidate stale cache lines
        for (int s2 = tid; s2 < NT; s2 += RPB) {
            double e2 = 0.0;
            #pragma unroll
            for (int k = 0; k < NSPLIT; ++k) e2 += part[s2 * NSPLIT + k];
            double e = ep[2 * s2] + e2;
            double p = ep[2 * s2 + 1];
            se_s[s2] = e * p;
            sp_s[s2] = p;
        }
        __syncthreads();
        if (tid < NT / 16) {
            double se = 0.0, sp = 0.0;
            #pragma unroll
            for (int u = 0; u < 16; ++u) {
                se += se_s[tid * 16 + u];
                sp += sp_s[tid * 16 + u];
            }
            out[tid] = (float)(se / sp);
        }
    }
}

extern "C" void kernel_launch(void* const* d_in, const int* in_sizes, int n_in,
                              void* d_out, int out_size, void* d_ws, size_t ws_size,
                              hipStream_t stream) {
    const float* mfv = (const float*)d_in[0];
    const float* h1  = (const float*)d_in[1];
    const float* h2  = (const float*)d_in[2];
    const int*   vn  = (const int*)d_in[3];
    const float* w   = (const float*)d_in[4];
    float* out = (float*)d_out;

    const int T = in_sizes[0] / (NORB * NFEAT);   // 256

    double*   ep   = (double*)d_ws;                        // 2T doubles
    double*   part = ep + 2 * NT;                          // NSPLIT*T doubles
    unsigned* ctr  = (unsigned*)((char*)d_ws + CTR_OFF);   // completion counter

    hipMemsetAsync(ctr, 0, sizeof(unsigned), stream);      // capture-legal memset node
    hipLaunchKernelGGL(eloc_fused, dim3(T * CPS), dim3(RPB), 0, stream,
                       mfv, h1, h2, vn, w, ep, part, ctr, out);
}

// Round 4
// 25.078 us; speedup vs baseline: 6.6705x; 6.6705x over previous
//
#include <hip/hip_runtime.h>

#define NORB   12
#define NFEAT  14
#define NCOL1  144
#define NCOL2  20736
#define RPB    192          // threads per block
#define NSPLIT 9            // two-body chunks per sample (9*192 = 1728 rows)
#define CPS    (NSPLIT + 1) // blocks per sample (chunk 0 = prep)
#define NT     256          // samples

// ---------------- Kernel 1: fused prep + two-body partials ----------------
extern "C" __global__ void __launch_bounds__(RPB)
eloc_fused(const float* __restrict__ mfv, const float* __restrict__ h1,
           const float* __restrict__ h2, const int* __restrict__ vn,
           const float* __restrict__ w,
           double* __restrict__ ep, double* __restrict__ part)
{
    const int tid = threadIdx.x;
    const int bid = blockIdx.x;
    const int t   = bid / CPS;
    const int ch  = bid % CPS;

    __shared__ float phi_s[NORB][NFEAT];
    __shared__ float ps_s[NORB];
    __shared__ int   x_s[NORB];
    __shared__ float Sv_s;
    __shared__ float W_s[NFEAT][NFEAT];
    __shared__ float tmp_s[NORB][NFEAT];
    __shared__ float G_s[NORB][NORB];
    __shared__ unsigned char m1_s[NCOL1];
    __shared__ int Ri_s[NORB], Rj_s[NORB], M_s;
    __shared__ double A1[NORB][NORB], A2[NORB][NORB];
    __shared__ double red_s[RPB / 64];
    __shared__ double det_s[2];
    __shared__ double h1sum_s;

    // ---- common: phi, x, ps, Sv, X2 ----
    if (tid < NORB * NFEAT)
        phi_s[tid / NFEAT][tid % NFEAT] = mfv[(size_t)t * NORB * NFEAT + tid];
    if (tid >= NORB * NFEAT && tid < NORB * NFEAT + NORB)
        x_s[tid - NORB * NFEAT] = vn[t * NORB + (tid - NORB * NFEAT)];
    __syncthreads();
    if (tid < NORB) {
        float s = 0.f;
        #pragma unroll
        for (int f = 0; f < NFEAT; ++f) s += phi_s[tid][f];
        ps_s[tid] = s;
    }
    __syncthreads();
    if (tid == 0) {
        float s = 0.f;
        for (int a = 0; a < NORB; ++a) s += ps_s[a] * (float)x_s[a];
        Sv_s = s;
    }
    __syncthreads();

    int X2 = 0;
    #pragma unroll
    for (int a = 0; a < NORB; ++a) X2 |= (x_s[a] == 2) ? (1 << a) : 0;
    const int nx2 = ~X2 & 0xFFF;
    const float Sv = Sv_s;

    if (ch != 0) {
        // ---------------- two-body chunk ----------------
        float psv[NORB];
        #pragma unroll
        for (int q = 0; q < NORB; ++q) psv[q] = ps_s[q];

        const int r = (ch - 1) * RPB + tid;             // 0..1727
        const int i = r / 144, j = (r / NORB) % NORB, p = r % NORB;

        const float4* hr = (const float4*)(h2 + (size_t)t * NCOL2 + (size_t)r * NORB);
        const float4 ha = hr[0], hb = hr[1], hc = hr[2];

        const int bi = 1 << i, bj = 1 << j, bp = 1 << p;
        const int um0 = 0xFFF & ~(bi | bj | bp);
        const int xi = 1 + ((X2 >> i) & 1);
        const int xj = 1 + ((X2 >> j) & 1);
        const int xp = 1 + ((X2 >> p) & 1);
        const int basei = xi + 1 - ((bi >> j) & 1) - ((bi >> p) & 1);
        const int basej = xj + ((bj >> i) & 1) - 1 - ((bj >> p) & 1);
        const int basep = xp + ((bp >> i) & 1) - ((bp >> j) & 1) - 1;
        const float a2b = Sv + psv[i] - psv[j] - psv[p];

        float acc = 0.f;
#define COLQ(q, hv) {                                                       \
        const int bq  = 1 << (q);                                           \
        const int um  = um0 & ~bq;                                          \
        const int hm1 = nx2 & um, hm2 = X2 & um;                            \
        int mn = hm1 ? 1 : (hm2 ? 2 : 9);                                   \
        int mx = hm2 ? 2 : (hm1 ? 1 : -9);                                  \
        const int iq = (bi >> (q)) & 1, jq = (bj >> (q)) & 1,               \
                  pq = (bp >> (q)) & 1;                                     \
        const int vi = basei + iq, vj = basej + jq, vp = basep + pq;        \
        const int xq = 1 + ((X2 >> (q)) & 1);                               \
        const int vq = xq + 1 + iq - jq - pq;                               \
        mn = min(min(mn, vi), min(vj, min(vp, vq)));                        \
        mx = max(max(mx, vi), max(vj, max(vp, vq)));                        \
        const bool ok = (mx - mn == 1) && ((hv) > 0.0f);                    \
        const float tq = ok ? (hv) * (a2b + psv[q]) : 0.0f;                 \
        acc = fmaf(tq, tq, acc);                                            \
    }
        COLQ(0,  ha.x)  COLQ(1,  ha.y)  COLQ(2,  ha.z)  COLQ(3,  ha.w)
        COLQ(4,  hb.x)  COLQ(5,  hb.y)  COLQ(6,  hb.z)  COLQ(7,  hb.w)
        COLQ(8,  hc.x)  COLQ(9,  hc.y)  COLQ(10, hc.z)  COLQ(11, hc.w)
#undef COLQ

        double accd = (double)acc;
        #pragma unroll
        for (int o = 32; o > 0; o >>= 1) accd += __shfl_down(accd, o, 64);
        const int wv = tid >> 6, lane = tid & 63;
        if (lane == 0) red_s[wv] = accd;
        __syncthreads();
        if (tid == 0) part[t * NSPLIT + (ch - 1)] = red_s[0] + red_s[1] + red_s[2];
    } else {
        // ---------------- prep chunk: G, one-body, determinants ----------------
        for (int k2 = tid; k2 < NFEAT * NFEAT; k2 += RPB) {
            int r2 = k2 / NFEAT, c2 = k2 % NFEAT;
            W_s[r2][c2] = w[k2] + w[c2 * NFEAT + r2];
        }
        __syncthreads();
        if (tid < NORB * NFEAT) {
            int a = tid / NFEAT, f = tid % NFEAT;
            float s = 0.f;
            #pragma unroll
            for (int g = 0; g < NFEAT; ++g) s += phi_s[a][g] * W_s[g][f];
            tmp_s[a][f] = s;
        }
        __syncthreads();
        if (tid < NCOL1) {
            int a = tid / NORB, i = tid % NORB;
            float s = 0.f;
            #pragma unroll
            for (int f = 0; f < NFEAT; ++f) s += tmp_s[a][f] * phi_s[i][f];
            G_s[a][i] = s;
        }

        // one-body mask + h1^2 sum
        double h1c = 0.0;
        if (tid < NCOL1) {
            int ii = tid / NORB, jj = tid % NORB;
            int um  = 0xFFF & ~((1 << ii) | (1 << jj));
            int hm1 = nx2 & um, hm2 = X2 & um;
            int mn = hm1 ? 1 : (hm2 ? 2 : 9);
            int mx = hm2 ? 2 : (hm1 ? 1 : -9);
            int d  = (ii == jj) ? 0 : 1;
            int vi = x_s[ii] - d, vj = x_s[jj] + d;
            mn = min(mn, min(vi, vj));
            mx = max(mx, max(vi, vj));
            float h1v = h1[(size_t)t * NCOL1 + tid];
            bool ok = (mx - mn == 1) && (h1v > 0.0f);
            m1_s[tid] = ok ? 1 : 0;
            if (ok) h1c = (double)h1v * (double)h1v;
        }
        __syncthreads();
        {
            #pragma unroll
            for (int o = 32; o > 0; o >>= 1) h1c += __shfl_down(h1c, o, 64);
            const int wv = tid >> 6, lane = tid & 63;
            if (lane == 0) red_s[wv] = h1c;
            __syncthreads();
            if (tid == 0) h1sum_s = red_s[0] + red_s[1] + red_s[2];
        }

        if (tid < NORB) {
            int ri = 0, rj = 0;
            #pragma unroll
            for (int o = 0; o < NORB; ++o) {
                ri += m1_s[tid * NORB + o];
                rj += m1_s[o * NORB + tid];
            }
            Ri_s[tid] = ri;
            Rj_s[tid] = rj;
        }
        __syncthreads();
        if (tid == 0) {
            int m = 0;
            #pragma unroll
            for (int o = 0; o < NORB; ++o) m += Ri_s[o];
            M_s = m;
        }
        __syncthreads();

        if (tid < NCOL1) {
            int a = tid / NORB, b = tid % NORB;
            int xa = x_s[a], xb = x_s[b];
            int Da = Rj_s[a] - Ri_s[a], Db = Rj_s[b] - Ri_s[b];
            int s1 = xa * xb * M_s + xa * Db + xb * Da
                   - (int)m1_s[b * NORB + a] - (int)m1_s[a * NORB + b];
            if (a == b) s1 += Rj_s[a] + Ri_s[a];
            A1[a][b] = (double)G_s[a][b] * (double)s1;
            A2[a][b] = (double)G_s[a][b];
        }
        __syncthreads();

        // barrier-free in-register LU with partial pivoting; wave0: A1, wave1: A2
        const int wv = tid >> 6, lane = tid & 63;
        if (wv < 2) {
            const double* Abase = (wv == 0) ? &A1[0][0] : &A2[0][0];
            const int rl = (lane < NORB) ? lane : 0;
            double a[NORB];
            #pragma unroll
            for (int c = 0; c < NORB; ++c) a[c] = Abase[rl * NORB + c];
            double det = 1.0;
            #pragma unroll
            for (int k = 0; k < NORB; ++k) {
                double key = (lane >= k && lane < NORB) ? fabs(a[k]) : -1.0;
                int idx = lane;
                #pragma unroll
                for (int off = 8; off >= 1; off >>= 1) {
                    double k2 = __shfl_xor(key, off);
                    int    i2 = __shfl_xor(idx, off);
                    if (k2 > key || (k2 == key && i2 < idx)) { key = k2; idx = i2; }
                }
                int pr = idx;
                if (pr != k) det = -det;
                int src = (lane == k) ? pr : ((lane == pr) ? k : lane);
                #pragma unroll
                for (int c = 0; c < NORB; ++c) a[c] = __shfl(a[c], src);
                double pk[NORB];
                #pragma unroll
                for (int c = 0; c < NORB; ++c) pk[c] = __shfl(a[c], k);
                double piv = pk[k];
                det *= piv;
                double inv = (piv != 0.0) ? 1.0 / piv : 0.0;
                double f = (lane > k && lane < NORB) ? a[k] * inv : 0.0;
                #pragma unroll
                for (int c = 0; c < NORB; ++c) a[c] = fma(-f, pk[c], a[c]);
            }
            if (lane == 0) det_s[wv] = det;
        }
        __syncthreads();

        if (tid == 0) {
            double e1 = det_s[0] * det_s[0] * h1sum_s;
            int n2 = __popc(X2);
            double pd = det_s[1] * (double)(1ull << (2 * n2));
            ep[2 * t]     = e1;
            ep[2 * t + 1] = pd * pd;
        }
    }
}

// ---------------- Kernel 2: combine ----------------
extern "C" __global__ void __launch_bounds__(256)
eloc_final(const double* __restrict__ ep, const double* __restrict__ part,
           float* __restrict__ out)
{
    const int s = threadIdx.x;
    __shared__ double se_s[NT], sp_s[NT];
    if (s < NT) {
        double e2 = 0.0;
        #pragma unroll
        for (int k = 0; k < NSPLIT; ++k) e2 += part[s * NSPLIT + k];
        double e = ep[2 * s] + e2;
        double p = ep[2 * s + 1];
        se_s[s] = e * p;
        sp_s[s] = p;
    }
    __syncthreads();
    if (s < NT / 16) {
        double se = 0.0, sp = 0.0;
        #pragma unroll
        for (int u = 0; u < 16; ++u) {
            se += se_s[s * 16 + u];
            sp += sp_s[s * 16 + u];
        }
        out[s] = (float)(se / sp);
    }
}

extern "C" void kernel_launch(void* const* d_in, const int* in_sizes, int n_in,
                              void* d_out, int out_size, void* d_ws, size_t ws_size,
                              hipStream_t stream) {
    const float* mfv = (const float*)d_in[0];
    const float* h1  = (const float*)d_in[1];
    const float* h2  = (const float*)d_in[2];
    const int*   vn  = (const int*)d_in[3];
    const float* w   = (const float*)d_in[4];
    float* out = (float*)d_out;

    double* ep   = (double*)d_ws;          // 2*NT doubles
    double* part = ep + 2 * NT;            // NSPLIT*NT doubles

    hipLaunchKernelGGL(eloc_fused, dim3(NT * CPS), dim3(RPB), 0, stream,
                       mfv, h1, h2, vn, w, ep, part);
    hipLaunchKernelGGL(eloc_final, dim3(1), dim3(256), 0, stream, ep, part, out);
}